// Round 11
// baseline (165.662 us; speedup 1.0000x reference)
//
#include <hip/hip_runtime.h>
#include <cfloat>
#include <cmath>

#define DIM 64
#define TT 2048
#define NTOT 65536
#define KE 1024

typedef _Float16 f16x8 __attribute__((ext_vector_type(8)));
typedef _Float16 f16x4 __attribute__((ext_vector_type(4)));
typedef float    f32x4 __attribute__((ext_vector_type(4)));

// ws layout (bytes):
//   keys   [0, 524288)        : 65536 u64, one per t, init 0xFF..F
//   planes [524288, 786432)   : fp16 hi plane (131072 B) + lo plane (131072 B)
//   e2     [786432, 790528)   : 1024 f32
// plane vector layout (B-fragment-ready, verified R5-R10): f16x8 index
//   ((g*2+k)*64 + l) for group g (16 codes), kstep k, lane l=q*16+ln holding
//   embed_plane[c=g*16+ln][j=k*32+q*8 .. +7].
#define WS_NEED 790528

// ============================ fast path ====================================
__global__ __launch_bounds__(256) void prep_kernel(
    const float* __restrict__ embed,
    _Float16* __restrict__ planes,
    float* __restrict__ e2g,
    unsigned long long* __restrict__ keys,
    float* __restrict__ counts,        // out_avg region  (zeroed here)
    float* __restrict__ distsum)       // out_commit slot (zeroed here)
{
    const int gidx = blockIdx.x * 256 + threadIdx.x;   // 8192 threads
    const int g  = gidx >> 7;
    const int k  = (gidx >> 6) & 1;
    const int l  = gidx & 63;
    const int q  = l >> 4;
    const int ln = l & 15;
    const int c  = g * 16 + ln;
    const int jb = k * 32 + q * 8;

    const float4 v0 = *(const float4*)(embed + (size_t)c * DIM + jb);
    const float4 v1 = *(const float4*)(embed + (size_t)c * DIM + jb + 4);
    const float xf[8] = {v0.x, v0.y, v0.z, v0.w, v1.x, v1.y, v1.z, v1.w};
    f16x8 h1, h2;
    #pragma unroll
    for (int e = 0; e < 8; ++e) {
        const _Float16 a = (_Float16)xf[e];
        h1[e] = a;
        h2[e] = (_Float16)(xf[e] - (float)a);   // exact residual
    }
    const int off = ((g * 2 + k) * 64 + l) * 8;
    *(f16x8*)(planes + off)         = h1;
    *(f16x8*)(planes + 65536 + off) = h2;

    // keys init (coalesced)
    #pragma unroll
    for (int i = 0; i < 8; ++i) keys[(size_t)i * 8192 + gidx] = ~0ull;

    if (gidx < KE) {
        const float4* rp = (const float4*)(embed + (size_t)gidx * DIM);
        float s = 0.f;
        #pragma unroll
        for (int i = 0; i < 16; ++i) {
            const float4 v = rp[i];
            s += v.x * v.x + v.y * v.y + v.z * v.z + v.w * v.w;
        }
        e2g[gidx]    = s;
        counts[gidx] = 0.f;
        if (gidx == 0) distsum[0] = 0.f;
    }
}

// Pass 1: grid 4096 = 512 t-tiles x 8 K-eighths. Block = 128 t x 128 codes.
// The block's whole B-slab (128 codes x 2 planes = 32 KB = a CONTIGUOUS run
// of `planes`) is copied to LDS once (8 x 16B per thread, coalesced), then
// the hot loop is ds_read_b128 + MFMA only — no global loads, no barriers.
// This breaks the R10 convoy (all waves stalled on the same L2 latency).
// (256,2) bounds: spill-free in every session build; (256,4) squeezed to
// 64 VGPR and spilled 250+ MB (R8/R9) — do not use.
__global__ __launch_bounds__(256, 2) void argmin_p1(
    const float* __restrict__ x,       // [B][D][T]
    const f16x8* __restrict__ P,       // ws planes
    const float* __restrict__ e2g,     // ws e2
    unsigned long long* __restrict__ keys,
    float* __restrict__ distsum)       // += sum(x^2) from kq==0 blocks
{
    __shared__ f16x8 bslab[2048];      // 32 KB: [plane][chunk(g*2+k)][lane]
    __shared__ float e2s[128];

    const int tid  = threadIdx.x;
    const int l    = tid & 63;
    const int w    = tid >> 6;
    const int q    = l >> 4;
    const int ln   = l & 15;
    const int bid  = blockIdx.x;
    const int kq   = bid & 7;          // K-eighth
    const int tile = bid >> 3;
    const int b    = tile >> 4;
    const int t0   = (tile & 15) << 7;

    // ---- stage B-slab: LDS word w <- P[p*8192 + kq*1024 + (w&1023)] ----
    #pragma unroll
    for (int i = 0; i < 8; ++i) {
        const int wd = i * 256 + tid;
        const int p  = wd >> 10;
        const int rm = wd & 1023;
        bslab[wd] = P[p * 8192 + kq * 1024 + rm];
    }
    if (tid < 32)
        *(float4*)&e2s[tid * 4] = *(const float4*)(e2g + kq * 128 + tid * 4);

    // ---- A fragments: fp16 split in registers (layout verified R5-R10) ----
    f16x8 af[2][2][2];                 // [plane][m][k]
    float x2p[2] = {0.f, 0.f};
    #pragma unroll
    for (int m = 0; m < 2; ++m)
        #pragma unroll
        for (int k = 0; k < 2; ++k)
            #pragma unroll
            for (int jj = 0; jj < 8; ++jj) {
                const int j = k * 32 + q * 8 + jj;
                const float xf = x[(size_t)(b * DIM + j) * TT + t0 + w * 32 + m * 16 + ln];
                const _Float16 h1 = (_Float16)xf;
                af[0][m][k][jj] = h1;
                af[1][m][k][jj] = (_Float16)(xf - (float)h1);
                x2p[m] = fmaf(xf, xf, x2p[m]);
            }
    __syncthreads();                   // bslab + e2s ready (only barrier)

    float bs[2][4];
    int   bi[2][4];
    #pragma unroll
    for (int m = 0; m < 2; ++m)
        #pragma unroll
        for (int r = 0; r < 4; ++r) { bs[m][r] = FLT_MAX; bi[m][r] = 0; }

    // ---- hot loop: 8 groups of 16 codes, pure LDS + MFMA ----
    for (int gl = 0; gl < 8; ++gl) {
        const int   wbase = gl * 128 + l;      // chunk (gl*2+0), lane l
        const f16x8 b1k0 = bslab[wbase];
        const f16x8 b1k1 = bslab[wbase + 64];
        const f16x8 b2k0 = bslab[1024 + wbase];
        const f16x8 b2k1 = bslab[1024 + wbase + 64];
        const int   cl   = gl * 16 + ln;
        const float e2c  = e2s[cl];
        const int   cgl  = kq * 128 + cl;
        #pragma unroll
        for (int m = 0; m < 2; ++m) {
            f32x4 C = {0.f, 0.f, 0.f, 0.f};
            // small terms first for accuracy (verified R5-R10 ordering)
            C = __builtin_amdgcn_mfma_f32_16x16x32_f16(af[1][m][0], b2k0, C, 0, 0, 0);
            C = __builtin_amdgcn_mfma_f32_16x16x32_f16(af[1][m][1], b2k1, C, 0, 0, 0);
            C = __builtin_amdgcn_mfma_f32_16x16x32_f16(af[1][m][0], b1k0, C, 0, 0, 0);
            C = __builtin_amdgcn_mfma_f32_16x16x32_f16(af[1][m][1], b1k1, C, 0, 0, 0);
            C = __builtin_amdgcn_mfma_f32_16x16x32_f16(af[0][m][0], b2k0, C, 0, 0, 0);
            C = __builtin_amdgcn_mfma_f32_16x16x32_f16(af[0][m][1], b2k1, C, 0, 0, 0);
            C = __builtin_amdgcn_mfma_f32_16x16x32_f16(af[0][m][0], b1k0, C, 0, 0, 0);
            C = __builtin_amdgcn_mfma_f32_16x16x32_f16(af[0][m][1], b1k1, C, 0, 0, 0);
            #pragma unroll
            for (int r = 0; r < 4; ++r) {
                const float s = fmaf(-2.f, C[r], e2c);
                // strict < + ascending c keeps lowest index on ties
                if (s < bs[m][r]) { bs[m][r] = s; bi[m][r] = cgl; }
            }
        }
    }

    // ---- reduce over the 16 code-columns, then device-wide atomicMin ----
    #pragma unroll
    for (int m = 0; m < 2; ++m)
        #pragma unroll
        for (int r = 0; r < 4; ++r) {
            float s = bs[m][r]; int i = bi[m][r];
            #pragma unroll
            for (int mask = 1; mask < 16; mask <<= 1) {
                const float s2 = __shfl_xor(s, mask);
                const int   i2 = __shfl_xor(i, mask);
                if (s2 < s || (s2 == s && i2 < i)) { s = s2; i = i2; }
            }
            if (ln == 0) {
                const int t_loc = w * 32 + m * 16 + q * 4 + r;   // C-row map (verified)
                unsigned int sb = __float_as_uint(s);
                sb = sb ^ (((unsigned int)(((int)sb) >> 31)) | 0x80000000u);
                const unsigned long long key =
                    ((unsigned long long)sb << 32) | (unsigned int)i;
                atomicMin(&keys[(size_t)b * TT + t0 + t_loc], key);
            }
        }

    // ---- sum(x^2): each wave covers its 32 t's exactly once (kq==0 only) ----
    if (kq == 0) {
        float v = x2p[0] + x2p[1];
        #pragma unroll
        for (int off = 1; off < 64; off <<= 1) v += __shfl_xor(v, off);
        if (l == 0) atomicAdd(distsum, v);
    }
}

// Pass 2: decode keys -> idx, counts, sum(s); gather quantized rows.
__global__ __launch_bounds__(256) void gather_p2(
    const unsigned long long* __restrict__ keys,
    const float* __restrict__ embed,
    float* __restrict__ out_q,
    float* __restrict__ out_idx,
    float* __restrict__ counts,
    float* __restrict__ distsum)
{
    __shared__ int   ibest[128];
    __shared__ float ssum[128];
    const int tid = threadIdx.x;
    const int n0  = blockIdx.x * 128;
    const int b   = n0 >> 11;          // TT = 2048
    const int t0  = n0 & 2047;

    if (tid < 128) {
        const unsigned long long key = keys[n0 + tid];
        const unsigned int idx = (unsigned int)(key & 0xFFFFFFFFull);
        unsigned int u = (unsigned int)(key >> 32);
        u = (u & 0x80000000u) ? (u ^ 0x80000000u) : ~u;   // inverse monotone map
        ibest[tid] = (int)idx;
        ssum[tid]  = __uint_as_float(u);                  // s = e^2 - 2 x.e
        out_idx[n0 + tid] = (float)idx;
        atomicAdd(&counts[idx], 1.0f);
    }
    __syncthreads();
    if (tid < 64) {
        float v = ssum[tid] + ssum[tid + 64];
        #pragma unroll
        for (int off = 1; off < 64; off <<= 1) v += __shfl_xor(v, off);
        if (tid == 0) atomicAdd(distsum, v);
    }
    // gather: out_q[b][j][t0+tt] = embed[ibest[tt]][j]  (embed L2-hot)
    #pragma unroll
    for (int p = 0; p < 32; ++p) {
        const int f  = p * 256 + tid;
        const int j  = f >> 7;
        const int tt = f & 127;
        out_q[(size_t)(b * DIM + j) * TT + t0 + tt] =
            embed[(size_t)ibest[tt] * DIM + j];
    }
}

// ======================= fallback path (Round-5, passed) ====================
#define EP_ROW   72
#define EP_PLANE 4608
#define SMEM_BYTES (36864 + 4096 + 512 + 512 + 16)

__global__ __launch_bounds__(256, 2) void argmin_fb(
    const float* __restrict__ x, const float* __restrict__ embed,
    float* __restrict__ out_q, float* __restrict__ out_idx,
    float* __restrict__ counts, float* __restrict__ distsum)
{
    __shared__ __align__(16) char smem[SMEM_BYTES];
    _Float16* ep  = (_Float16*)smem;
    float* e2s    = (float*)(smem + 36864);
    float* x2s    = (float*)(smem + 36864 + 4096);
    int*   ibest  = (int*)  (smem + 36864 + 4608);
    float* mdsum  = (float*)(smem + 36864 + 5120);

    const int tid = threadIdx.x;
    const int l   = tid & 63;
    const int w   = tid >> 6;
    const int q   = l >> 4;
    const int ln  = l & 15;
    const int bid = blockIdx.x;
    const int b   = bid >> 4;
    const int t0  = (bid & 15) << 7;

    if (tid == 0) mdsum[0] = 0.f;
    #pragma unroll
    for (int pass = 0; pass < 4; ++pass) {
        const int c = pass * 256 + tid;
        const float4* rp = (const float4*)(embed + (size_t)c * DIM);
        float s = 0.f;
        #pragma unroll
        for (int i = 0; i < 16; ++i) {
            const float4 v = rp[i];
            s += v.x * v.x + v.y * v.y + v.z * v.z + v.w * v.w;
        }
        e2s[c] = s;
    }
    f16x8 af[2][2][2];
    float x2p[2] = {0.f, 0.f};
    #pragma unroll
    for (int m = 0; m < 2; ++m)
        #pragma unroll
        for (int k = 0; k < 2; ++k)
            #pragma unroll
            for (int jj = 0; jj < 8; ++jj) {
                const int j = k * 32 + q * 8 + jj;
                const float xf = x[(size_t)(b * DIM + j) * TT + t0 + w * 32 + m * 16 + ln];
                const _Float16 h1 = (_Float16)xf;
                af[0][m][k][jj] = h1;
                af[1][m][k][jj] = (_Float16)(xf - (float)h1);
                x2p[m] = fmaf(xf, xf, x2p[m]);
            }
    #pragma unroll
    for (int m = 0; m < 2; ++m) {
        x2p[m] += __shfl_xor(x2p[m], 16);
        x2p[m] += __shfl_xor(x2p[m], 32);
    }
    if (q == 0) { x2s[w * 32 + ln] = x2p[0]; x2s[w * 32 + 16 + ln] = x2p[1]; }
    {
        #pragma unroll
        for (int pass = 0; pass < 4; ++pass) {
            const int c_loc = (tid >> 4) + pass * 16;
            const int j4    = (tid & 15) * 4;
            const float4 v = *(const float4*)(embed + (size_t)c_loc * DIM + j4);
            f16x4 h1, h2;
            h1[0] = (_Float16)v.x; h2[0] = (_Float16)(v.x - (float)h1[0]);
            h1[1] = (_Float16)v.y; h2[1] = (_Float16)(v.y - (float)h1[1]);
            h1[2] = (_Float16)v.z; h2[2] = (_Float16)(v.z - (float)h1[2]);
            h1[3] = (_Float16)v.w; h2[3] = (_Float16)(v.w - (float)h1[3]);
            *(f16x4*)(ep + c_loc * EP_ROW + j4)            = h1;
            *(f16x4*)(ep + EP_PLANE + c_loc * EP_ROW + j4) = h2;
        }
    }
    __syncthreads();
    float bs[2][4]; int bi[2][4];
    #pragma unroll
    for (int m = 0; m < 2; ++m)
        #pragma unroll
        for (int r = 0; r < 4; ++r) { bs[m][r] = FLT_MAX; bi[m][r] = 0; }
    for (int kc = 0; kc < 16; ++kc) {
        const int cur = kc & 1, nxt = cur ^ 1;
        float4 ev[4];
        if (kc < 15)
            #pragma unroll
            for (int pass = 0; pass < 4; ++pass) {
                const int c_loc = (tid >> 4) + pass * 16;
                const int j4    = (tid & 15) * 4;
                ev[pass] = *(const float4*)(embed + (size_t)((kc + 1) * 64 + c_loc) * DIM + j4);
            }
        const _Float16* p1 = ep + cur * 2 * EP_PLANE;
        const _Float16* p2 = p1 + EP_PLANE;
        #pragma unroll
        for (int n = 0; n < 4; ++n) {
            const int coff = (n * 16 + ln) * EP_ROW + q * 8;
            const f16x8 b1k0 = *(const f16x8*)(p1 + coff);
            const f16x8 b1k1 = *(const f16x8*)(p1 + coff + 32);
            const f16x8 b2k0 = *(const f16x8*)(p2 + coff);
            const f16x8 b2k1 = *(const f16x8*)(p2 + coff + 32);
            const int   c_lane = kc * 64 + n * 16 + ln;
            const float e2c    = e2s[c_lane];
            #pragma unroll
            for (int m = 0; m < 2; ++m) {
                f32x4 C = {0.f, 0.f, 0.f, 0.f};
                C = __builtin_amdgcn_mfma_f32_16x16x32_f16(af[1][m][0], b2k0, C, 0, 0, 0);
                C = __builtin_amdgcn_mfma_f32_16x16x32_f16(af[1][m][1], b2k1, C, 0, 0, 0);
                C = __builtin_amdgcn_mfma_f32_16x16x32_f16(af[1][m][0], b1k0, C, 0, 0, 0);
                C = __builtin_amdgcn_mfma_f32_16x16x32_f16(af[1][m][1], b1k1, C, 0, 0, 0);
                C = __builtin_amdgcn_mfma_f32_16x16x32_f16(af[0][m][0], b2k0, C, 0, 0, 0);
                C = __builtin_amdgcn_mfma_f32_16x16x32_f16(af[0][m][1], b2k1, C, 0, 0, 0);
                C = __builtin_amdgcn_mfma_f32_16x16x32_f16(af[0][m][0], b1k0, C, 0, 0, 0);
                C = __builtin_amdgcn_mfma_f32_16x16x32_f16(af[0][m][1], b1k1, C, 0, 0, 0);
                #pragma unroll
                for (int r = 0; r < 4; ++r) {
                    const float s = fmaf(-2.f, C[r], e2c);
                    if (s < bs[m][r]) { bs[m][r] = s; bi[m][r] = c_lane; }
                }
            }
        }
        if (kc < 15) {
            _Float16* w1 = ep + nxt * 2 * EP_PLANE;
            _Float16* w2 = w1 + EP_PLANE;
            #pragma unroll
            for (int pass = 0; pass < 4; ++pass) {
                const int c_loc = (tid >> 4) + pass * 16;
                const int j4    = (tid & 15) * 4;
                const float4 v = ev[pass];
                f16x4 h1, h2;
                h1[0] = (_Float16)v.x; h2[0] = (_Float16)(v.x - (float)h1[0]);
                h1[1] = (_Float16)v.y; h2[1] = (_Float16)(v.y - (float)h1[1]);
                h1[2] = (_Float16)v.z; h2[2] = (_Float16)(v.z - (float)h1[2]);
                h1[3] = (_Float16)v.w; h2[3] = (_Float16)(v.w - (float)h1[3]);
                *(f16x4*)(w1 + c_loc * EP_ROW + j4) = h1;
                *(f16x4*)(w2 + c_loc * EP_ROW + j4) = h2;
            }
        }
        __syncthreads();
    }
    float mdloc = 0.f;
    #pragma unroll
    for (int m = 0; m < 2; ++m)
        #pragma unroll
        for (int r = 0; r < 4; ++r) {
            float s = bs[m][r]; int i = bi[m][r];
            #pragma unroll
            for (int mask = 1; mask < 16; mask <<= 1) {
                const float s2 = __shfl_xor(s, mask);
                const int   i2 = __shfl_xor(i, mask);
                if (s2 < s || (s2 == s && i2 < i)) { s = s2; i = i2; }
            }
            if (ln == 0) {
                const int t_loc = w * 32 + m * 16 + q * 4 + r;
                ibest[t_loc] = i;
                out_idx[b * TT + t0 + t_loc] = (float)i;
                atomicAdd(&counts[i], 1.0f);
                mdloc += x2s[t_loc] + s;
            }
        }
    if (ln == 0) atomicAdd(mdsum, mdloc);
    __syncthreads();
    if (tid == 0) atomicAdd(distsum, mdsum[0]);
    #pragma unroll
    for (int p = 0; p < 32; ++p) {
        const int f  = p * 256 + tid;
        const int j  = f >> 7;
        const int tt = f & 127;
        out_q[(size_t)(b * DIM + j) * TT + t0 + tt] =
            embed[(size_t)ibest[tt] * DIM + j];
    }
}

// finalize: in-place counts->avg_probs, perplexity, usage, commitment
__global__ __launch_bounds__(1024) void finalize_kernel(
    float* __restrict__ avg, float* __restrict__ commit_slot,
    float* __restrict__ out_perp, float* __restrict__ out_usage)
{
    __shared__ float s_ent[1024];
    __shared__ float s_use[1024];
    const int k = threadIdx.x;
    const float p = avg[k] * (1.0f / (float)NTOT);
    avg[k] = p;
    s_ent[k] = p * logf(p + 1e-10f);
    s_use[k] = p * logf(p * 1024.f + 1e-10f);
    __syncthreads();
    for (int off = 512; off > 0; off >>= 1) {
        if (k < off) { s_ent[k] += s_ent[k + off]; s_use[k] += s_use[k + off]; }
        __syncthreads();
    }
    if (k == 0) {
        const float ds = commit_slot[0];
        *out_perp      = expf(-s_ent[0]);
        *out_usage     = s_use[0];
        commit_slot[0] = 0.25f * ds * (1.0f / ((float)NTOT * (float)DIM));
    }
}

extern "C" void kernel_launch(void* const* d_in, const int* in_sizes, int n_in,
                              void* d_out, int out_size, void* d_ws, size_t ws_size,
                              hipStream_t stream) {
    const float* x     = (const float*)d_in[0];
    const float* embed = (const float*)d_in[1];

    float* out        = (float*)d_out;
    float* out_q      = out;             // 4194304
    float* out_commit = out + 4194304;   // distsum accumulator first
    float* out_perp   = out + 4194305;
    float* out_avg    = out + 4194306;   // counts accumulator first
    float* out_idx    = out + 4195330;
    // usage at out + 4260866

    if (ws_size >= WS_NEED) {
        unsigned long long* keys = (unsigned long long*)d_ws;
        _Float16* planes = (_Float16*)((char*)d_ws + 524288);
        float*    e2g    = (float*)((char*)d_ws + 786432);
        prep_kernel<<<32, 256, 0, stream>>>(embed, planes, e2g, keys, out_avg, out_commit);
        argmin_p1<<<4096, 256, 0, stream>>>(x, (const f16x8*)planes, e2g, keys, out_commit);
        gather_p2<<<512, 256, 0, stream>>>(keys, embed, out_q, out_idx, out_avg, out_commit);
    } else {
        hipMemsetAsync(out_commit, 0, 1026 * sizeof(float), stream);
        argmin_fb<<<512, 256, 0, stream>>>(x, embed, out_q, out_idx, out_avg, out_commit);
    }
    finalize_kernel<<<1, 1024, 0, stream>>>(out_avg, out_commit, out_perp, out + 4260866);
}

// Round 12
// 153.960 us; speedup vs baseline: 1.0760x; 1.0760x over previous
//
#include <hip/hip_runtime.h>
#include <cfloat>
#include <cmath>

#define DIM 64
#define TT 2048
#define NTOT 65536
#define KE 1024

typedef _Float16 f16x8 __attribute__((ext_vector_type(8)));
typedef _Float16 f16x4 __attribute__((ext_vector_type(4)));
typedef float    f32x4 __attribute__((ext_vector_type(4)));

// ws layout (bytes):
//   keys   [0, 524288)        : 65536 u64, one per t, init 0xFF..F
//   planes [524288, 786432)   : fp16 hi plane (131072 B) + lo plane (131072 B)
//   e2     [786432, 790528)   : 1024 f32
// plane vector layout (B-fragment-ready, verified R5-R11): f16x8 index
//   ((g*2+k)*64 + l) for group g (16 codes), kstep k, lane l=q*16+ln holding
//   embed_plane[c=g*16+ln][j=k*32+q*8 .. +7].
#define WS_NEED 790528

// ============================ fast path ====================================
__global__ __launch_bounds__(256) void prep_kernel(
    const float* __restrict__ embed,
    _Float16* __restrict__ planes,
    float* __restrict__ e2g,
    unsigned long long* __restrict__ keys,
    float* __restrict__ counts,        // out_avg region  (zeroed here)
    float* __restrict__ distsum)       // out_commit slot (zeroed here)
{
    const int gidx = blockIdx.x * 256 + threadIdx.x;   // 8192 threads
    const int g  = gidx >> 7;
    const int k  = (gidx >> 6) & 1;
    const int l  = gidx & 63;
    const int q  = l >> 4;
    const int ln = l & 15;
    const int c  = g * 16 + ln;
    const int jb = k * 32 + q * 8;

    const float4 v0 = *(const float4*)(embed + (size_t)c * DIM + jb);
    const float4 v1 = *(const float4*)(embed + (size_t)c * DIM + jb + 4);
    const float xf[8] = {v0.x, v0.y, v0.z, v0.w, v1.x, v1.y, v1.z, v1.w};
    f16x8 h1, h2;
    #pragma unroll
    for (int e = 0; e < 8; ++e) {
        const _Float16 a = (_Float16)xf[e];
        h1[e] = a;
        h2[e] = (_Float16)(xf[e] - (float)a);   // exact residual
    }
    const int off = ((g * 2 + k) * 64 + l) * 8;
    *(f16x8*)(planes + off)         = h1;
    *(f16x8*)(planes + 65536 + off) = h2;

    // keys init (coalesced)
    #pragma unroll
    for (int i = 0; i < 8; ++i) keys[(size_t)i * 8192 + gidx] = ~0ull;

    if (gidx < KE) {
        const float4* rp = (const float4*)(embed + (size_t)gidx * DIM);
        float s = 0.f;
        #pragma unroll
        for (int i = 0; i < 16; ++i) {
            const float4 v = rp[i];
            s += v.x * v.x + v.y * v.y + v.z * v.z + v.w * v.w;
        }
        e2g[gidx]    = s;
        counts[gidx] = 0.f;
        if (gidx == 0) distsum[0] = 0.f;
    }
}

// Pass 1: grid 1024 = 256 t-tiles(256 t) x 4 K-quarters. Wave owns 64 t as
// 4 M-tiles; per group: 4 global b128 B-loads feed 24 MFMA (6 MFMA/load —
// 1.5x R7's intensity), 3-product split (lo*lo dropped: adds ~1e-5 to
// distances, an order below the passing fp16-split error; MFMA floor
// 16.5 -> 12.4 us). Rolled (unroll 1) hot loop + (256,2): the only
// combination that never spilled this session (R8/R9: (256,4) squeezed to
// 64 VGPR = 250+ MB scratch; 16-iter loops auto-unroll).
__global__ __launch_bounds__(256, 2) void argmin_p1(
    const float* __restrict__ x,       // [B][D][T]
    const f16x8* __restrict__ P,       // ws planes
    const float* __restrict__ e2g,     // ws e2
    unsigned long long* __restrict__ keys,
    float* __restrict__ distsum)       // += sum(x^2) from kq==0 blocks
{
    __shared__ float e2s[256];

    const int tid  = threadIdx.x;
    const int l    = tid & 63;
    const int w    = tid >> 6;
    const int q    = l >> 4;
    const int ln   = l & 15;
    const int bid  = blockIdx.x;
    const int kq   = bid & 3;          // K-quarter
    const int tile = bid >> 2;         // 256 tiles of 256 t
    const int b    = tile >> 3;        // 8 tiles per batch row
    const int t0   = (tile & 7) << 8;

    if (tid < 64)
        *(float4*)&e2s[tid * 4] = *(const float4*)(e2g + kq * 256 + tid * 4);

    // ---- A fragments: 4 M-tiles/wave, fp16 split in registers ----
    f16x8 ah[4][2];                    // hi plane [m][k]
    f16x8 al[4][2];                    // lo plane [m][k]
    float x2p = 0.f;
    #pragma unroll
    for (int m = 0; m < 4; ++m)
        #pragma unroll
        for (int k = 0; k < 2; ++k)
            #pragma unroll
            for (int jj = 0; jj < 8; ++jj) {
                const int j = k * 32 + q * 8 + jj;
                const float xf = x[(size_t)(b * DIM + j) * TT + t0 + w * 64 + m * 16 + ln];
                const _Float16 h1 = (_Float16)xf;
                ah[m][k][jj] = h1;
                al[m][k][jj] = (_Float16)(xf - (float)h1);
                x2p = fmaf(xf, xf, x2p);
            }
    __syncthreads();                   // e2s ready

    float bs[4][4];
    int   bi[4][4];
    #pragma unroll
    for (int m = 0; m < 4; ++m)
        #pragma unroll
        for (int r = 0; r < 4; ++r) { bs[m][r] = FLT_MAX; bi[m][r] = 0; }

    // ---- hot loop: 16 groups of 16 codes from this K-quarter ----
    const f16x8* base = P + l + kq * 2048;
    #pragma unroll 1
    for (int gl = 0; gl < 16; ++gl) {
        const f16x8* gp = base + gl * 128;
        const f16x8 b1k0 = gp[0];          // hi plane
        const f16x8 b1k1 = gp[64];
        const f16x8 b2k0 = gp[8192];       // lo plane
        const f16x8 b2k1 = gp[8192 + 64];
        const int   cl   = gl * 16 + ln;
        const float e2c  = e2s[cl];
        const int   cgl  = kq * 256 + cl;
        #pragma unroll
        for (int m = 0; m < 4; ++m) {
            f32x4 C = {0.f, 0.f, 0.f, 0.f};
            // 3-product split, small terms first (lo*hi, hi*lo, then hi*hi)
            C = __builtin_amdgcn_mfma_f32_16x16x32_f16(al[m][0], b1k0, C, 0, 0, 0);
            C = __builtin_amdgcn_mfma_f32_16x16x32_f16(al[m][1], b1k1, C, 0, 0, 0);
            C = __builtin_amdgcn_mfma_f32_16x16x32_f16(ah[m][0], b2k0, C, 0, 0, 0);
            C = __builtin_amdgcn_mfma_f32_16x16x32_f16(ah[m][1], b2k1, C, 0, 0, 0);
            C = __builtin_amdgcn_mfma_f32_16x16x32_f16(ah[m][0], b1k0, C, 0, 0, 0);
            C = __builtin_amdgcn_mfma_f32_16x16x32_f16(ah[m][1], b1k1, C, 0, 0, 0);
            #pragma unroll
            for (int r = 0; r < 4; ++r) {
                const float s = fmaf(-2.f, C[r], e2c);
                // strict < + ascending c keeps lowest index on ties
                if (s < bs[m][r]) { bs[m][r] = s; bi[m][r] = cgl; }
            }
        }
    }

    // ---- reduce over the 16 code-columns, then device-wide atomicMin ----
    #pragma unroll
    for (int m = 0; m < 4; ++m)
        #pragma unroll
        for (int r = 0; r < 4; ++r) {
            float s = bs[m][r]; int i = bi[m][r];
            #pragma unroll
            for (int mask = 1; mask < 16; mask <<= 1) {
                const float s2 = __shfl_xor(s, mask);
                const int   i2 = __shfl_xor(i, mask);
                if (s2 < s || (s2 == s && i2 < i)) { s = s2; i = i2; }
            }
            if (ln == 0) {
                const int t_loc = w * 64 + m * 16 + q * 4 + r;   // C-row map (verified)
                unsigned int sb = __float_as_uint(s);
                sb = sb ^ (((unsigned int)(((int)sb) >> 31)) | 0x80000000u);
                const unsigned long long key =
                    ((unsigned long long)sb << 32) | (unsigned int)i;
                atomicMin(&keys[(size_t)b * TT + t0 + t_loc], key);
            }
        }

    // ---- sum(x^2): wave covers its 64 t x 64 j exactly once (kq==0 only) ----
    if (kq == 0) {
        float v = x2p;
        #pragma unroll
        for (int off = 1; off < 64; off <<= 1) v += __shfl_xor(v, off);
        if (l == 0) atomicAdd(distsum, v);
    }
}

// Pass 2: decode keys -> idx, counts, sum(s); gather quantized rows.
__global__ __launch_bounds__(256) void gather_p2(
    const unsigned long long* __restrict__ keys,
    const float* __restrict__ embed,
    float* __restrict__ out_q,
    float* __restrict__ out_idx,
    float* __restrict__ counts,
    float* __restrict__ distsum)
{
    __shared__ int   ibest[128];
    __shared__ float ssum[128];
    const int tid = threadIdx.x;
    const int n0  = blockIdx.x * 128;
    const int b   = n0 >> 11;          // TT = 2048
    const int t0  = n0 & 2047;

    if (tid < 128) {
        const unsigned long long key = keys[n0 + tid];
        const unsigned int idx = (unsigned int)(key & 0xFFFFFFFFull);
        unsigned int u = (unsigned int)(key >> 32);
        u = (u & 0x80000000u) ? (u ^ 0x80000000u) : ~u;   // inverse monotone map
        ibest[tid] = (int)idx;
        ssum[tid]  = __uint_as_float(u);                  // s = e^2 - 2 x.e
        out_idx[n0 + tid] = (float)idx;
        atomicAdd(&counts[idx], 1.0f);
    }
    __syncthreads();
    if (tid < 64) {
        float v = ssum[tid] + ssum[tid + 64];
        #pragma unroll
        for (int off = 1; off < 64; off <<= 1) v += __shfl_xor(v, off);
        if (tid == 0) atomicAdd(distsum, v);
    }
    // gather: out_q[b][j][t0+tt] = embed[ibest[tt]][j]  (embed L2-hot)
    #pragma unroll
    for (int p = 0; p < 32; ++p) {
        const int f  = p * 256 + tid;
        const int j  = f >> 7;
        const int tt = f & 127;
        out_q[(size_t)(b * DIM + j) * TT + t0 + tt] =
            embed[(size_t)ibest[tt] * DIM + j];
    }
}

// ======================= fallback path (Round-5, passed) ====================
#define EP_ROW   72
#define EP_PLANE 4608
#define SMEM_BYTES (36864 + 4096 + 512 + 512 + 16)

__global__ __launch_bounds__(256, 2) void argmin_fb(
    const float* __restrict__ x, const float* __restrict__ embed,
    float* __restrict__ out_q, float* __restrict__ out_idx,
    float* __restrict__ counts, float* __restrict__ distsum)
{
    __shared__ __align__(16) char smem[SMEM_BYTES];
    _Float16* ep  = (_Float16*)smem;
    float* e2s    = (float*)(smem + 36864);
    float* x2s    = (float*)(smem + 36864 + 4096);
    int*   ibest  = (int*)  (smem + 36864 + 4608);
    float* mdsum  = (float*)(smem + 36864 + 5120);

    const int tid = threadIdx.x;
    const int l   = tid & 63;
    const int w   = tid >> 6;
    const int q   = l >> 4;
    const int ln  = l & 15;
    const int bid = blockIdx.x;
    const int b   = bid >> 4;
    const int t0  = (bid & 15) << 7;

    if (tid == 0) mdsum[0] = 0.f;
    #pragma unroll
    for (int pass = 0; pass < 4; ++pass) {
        const int c = pass * 256 + tid;
        const float4* rp = (const float4*)(embed + (size_t)c * DIM);
        float s = 0.f;
        #pragma unroll
        for (int i = 0; i < 16; ++i) {
            const float4 v = rp[i];
            s += v.x * v.x + v.y * v.y + v.z * v.z + v.w * v.w;
        }
        e2s[c] = s;
    }
    f16x8 af[2][2][2];
    float x2p[2] = {0.f, 0.f};
    #pragma unroll
    for (int m = 0; m < 2; ++m)
        #pragma unroll
        for (int k = 0; k < 2; ++k)
            #pragma unroll
            for (int jj = 0; jj < 8; ++jj) {
                const int j = k * 32 + q * 8 + jj;
                const float xf = x[(size_t)(b * DIM + j) * TT + t0 + w * 32 + m * 16 + ln];
                const _Float16 h1 = (_Float16)xf;
                af[0][m][k][jj] = h1;
                af[1][m][k][jj] = (_Float16)(xf - (float)h1);
                x2p[m] = fmaf(xf, xf, x2p[m]);
            }
    #pragma unroll
    for (int m = 0; m < 2; ++m) {
        x2p[m] += __shfl_xor(x2p[m], 16);
        x2p[m] += __shfl_xor(x2p[m], 32);
    }
    if (q == 0) { x2s[w * 32 + ln] = x2p[0]; x2s[w * 32 + 16 + ln] = x2p[1]; }
    {
        #pragma unroll
        for (int pass = 0; pass < 4; ++pass) {
            const int c_loc = (tid >> 4) + pass * 16;
            const int j4    = (tid & 15) * 4;
            const float4 v = *(const float4*)(embed + (size_t)c_loc * DIM + j4);
            f16x4 h1, h2;
            h1[0] = (_Float16)v.x; h2[0] = (_Float16)(v.x - (float)h1[0]);
            h1[1] = (_Float16)v.y; h2[1] = (_Float16)(v.y - (float)h1[1]);
            h1[2] = (_Float16)v.z; h2[2] = (_Float16)(v.z - (float)h1[2]);
            h1[3] = (_Float16)v.w; h2[3] = (_Float16)(v.w - (float)h1[3]);
            *(f16x4*)(ep + c_loc * EP_ROW + j4)            = h1;
            *(f16x4*)(ep + EP_PLANE + c_loc * EP_ROW + j4) = h2;
        }
    }
    __syncthreads();
    float bs[2][4]; int bi[2][4];
    #pragma unroll
    for (int m = 0; m < 2; ++m)
        #pragma unroll
        for (int r = 0; r < 4; ++r) { bs[m][r] = FLT_MAX; bi[m][r] = 0; }
    for (int kc = 0; kc < 16; ++kc) {
        const int cur = kc & 1, nxt = cur ^ 1;
        float4 ev[4];
        if (kc < 15)
            #pragma unroll
            for (int pass = 0; pass < 4; ++pass) {
                const int c_loc = (tid >> 4) + pass * 16;
                const int j4    = (tid & 15) * 4;
                ev[pass] = *(const float4*)(embed + (size_t)((kc + 1) * 64 + c_loc) * DIM + j4);
            }
        const _Float16* p1 = ep + cur * 2 * EP_PLANE;
        const _Float16* p2 = p1 + EP_PLANE;
        #pragma unroll
        for (int n = 0; n < 4; ++n) {
            const int coff = (n * 16 + ln) * EP_ROW + q * 8;
            const f16x8 b1k0 = *(const f16x8*)(p1 + coff);
            const f16x8 b1k1 = *(const f16x8*)(p1 + coff + 32);
            const f16x8 b2k0 = *(const f16x8*)(p2 + coff);
            const f16x8 b2k1 = *(const f16x8*)(p2 + coff + 32);
            const int   c_lane = kc * 64 + n * 16 + ln;
            const float e2c    = e2s[c_lane];
            #pragma unroll
            for (int m = 0; m < 2; ++m) {
                f32x4 C = {0.f, 0.f, 0.f, 0.f};
                C = __builtin_amdgcn_mfma_f32_16x16x32_f16(af[1][m][0], b2k0, C, 0, 0, 0);
                C = __builtin_amdgcn_mfma_f32_16x16x32_f16(af[1][m][1], b2k1, C, 0, 0, 0);
                C = __builtin_amdgcn_mfma_f32_16x16x32_f16(af[1][m][0], b1k0, C, 0, 0, 0);
                C = __builtin_amdgcn_mfma_f32_16x16x32_f16(af[1][m][1], b1k1, C, 0, 0, 0);
                C = __builtin_amdgcn_mfma_f32_16x16x32_f16(af[0][m][0], b2k0, C, 0, 0, 0);
                C = __builtin_amdgcn_mfma_f32_16x16x32_f16(af[0][m][1], b2k1, C, 0, 0, 0);
                C = __builtin_amdgcn_mfma_f32_16x16x32_f16(af[0][m][0], b1k0, C, 0, 0, 0);
                C = __builtin_amdgcn_mfma_f32_16x16x32_f16(af[0][m][1], b1k1, C, 0, 0, 0);
                #pragma unroll
                for (int r = 0; r < 4; ++r) {
                    const float s = fmaf(-2.f, C[r], e2c);
                    if (s < bs[m][r]) { bs[m][r] = s; bi[m][r] = c_lane; }
                }
            }
        }
        if (kc < 15) {
            _Float16* w1 = ep + nxt * 2 * EP_PLANE;
            _Float16* w2 = w1 + EP_PLANE;
            #pragma unroll
            for (int pass = 0; pass < 4; ++pass) {
                const int c_loc = (tid >> 4) + pass * 16;
                const int j4    = (tid & 15) * 4;
                const float4 v = ev[pass];
                f16x4 h1, h2;
                h1[0] = (_Float16)v.x; h2[0] = (_Float16)(v.x - (float)h1[0]);
                h1[1] = (_Float16)v.y; h2[1] = (_Float16)(v.y - (float)h1[1]);
                h1[2] = (_Float16)v.z; h2[2] = (_Float16)(v.z - (float)h1[2]);
                h1[3] = (_Float16)v.w; h2[3] = (_Float16)(v.w - (float)h1[3]);
                *(f16x4*)(w1 + c_loc * EP_ROW + j4) = h1;
                *(f16x4*)(w2 + c_loc * EP_ROW + j4) = h2;
            }
        }
        __syncthreads();
    }
    float mdloc = 0.f;
    #pragma unroll
    for (int m = 0; m < 2; ++m)
        #pragma unroll
        for (int r = 0; r < 4; ++r) {
            float s = bs[m][r]; int i = bi[m][r];
            #pragma unroll
            for (int mask = 1; mask < 16; mask <<= 1) {
                const float s2 = __shfl_xor(s, mask);
                const int   i2 = __shfl_xor(i, mask);
                if (s2 < s || (s2 == s && i2 < i)) { s = s2; i = i2; }
            }
            if (ln == 0) {
                const int t_loc = w * 32 + m * 16 + q * 4 + r;
                ibest[t_loc] = i;
                out_idx[b * TT + t0 + t_loc] = (float)i;
                atomicAdd(&counts[i], 1.0f);
                mdloc += x2s[t_loc] + s;
            }
        }
    if (ln == 0) atomicAdd(mdsum, mdloc);
    __syncthreads();
    if (tid == 0) atomicAdd(distsum, mdsum[0]);
    #pragma unroll
    for (int p = 0; p < 32; ++p) {
        const int f  = p * 256 + tid;
        const int j  = f >> 7;
        const int tt = f & 127;
        out_q[(size_t)(b * DIM + j) * TT + t0 + tt] =
            embed[(size_t)ibest[tt] * DIM + j];
    }
}

// finalize: in-place counts->avg_probs, perplexity, usage, commitment
__global__ __launch_bounds__(1024) void finalize_kernel(
    float* __restrict__ avg, float* __restrict__ commit_slot,
    float* __restrict__ out_perp, float* __restrict__ out_usage)
{
    __shared__ float s_ent[1024];
    __shared__ float s_use[1024];
    const int k = threadIdx.x;
    const float p = avg[k] * (1.0f / (float)NTOT);
    avg[k] = p;
    s_ent[k] = p * logf(p + 1e-10f);
    s_use[k] = p * logf(p * 1024.f + 1e-10f);
    __syncthreads();
    for (int off = 512; off > 0; off >>= 1) {
        if (k < off) { s_ent[k] += s_ent[k + off]; s_use[k] += s_use[k + off]; }
        __syncthreads();
    }
    if (k == 0) {
        const float ds = commit_slot[0];
        *out_perp      = expf(-s_ent[0]);
        *out_usage     = s_use[0];
        commit_slot[0] = 0.25f * ds * (1.0f / ((float)NTOT * (float)DIM));
    }
}

extern "C" void kernel_launch(void* const* d_in, const int* in_sizes, int n_in,
                              void* d_out, int out_size, void* d_ws, size_t ws_size,
                              hipStream_t stream) {
    const float* x     = (const float*)d_in[0];
    const float* embed = (const float*)d_in[1];

    float* out        = (float*)d_out;
    float* out_q      = out;             // 4194304
    float* out_commit = out + 4194304;   // distsum accumulator first
    float* out_perp   = out + 4194305;
    float* out_avg    = out + 4194306;   // counts accumulator first
    float* out_idx    = out + 4195330;
    // usage at out + 4260866

    if (ws_size >= WS_NEED) {
        unsigned long long* keys = (unsigned long long*)d_ws;
        _Float16* planes = (_Float16*)((char*)d_ws + 524288);
        float*    e2g    = (float*)((char*)d_ws + 786432);
        prep_kernel<<<32, 256, 0, stream>>>(embed, planes, e2g, keys, out_avg, out_commit);
        argmin_p1<<<1024, 256, 0, stream>>>(x, (const f16x8*)planes, e2g, keys, out_commit);
        gather_p2<<<512, 256, 0, stream>>>(keys, embed, out_q, out_idx, out_avg, out_commit);
    } else {
        hipMemsetAsync(out_commit, 0, 1026 * sizeof(float), stream);
        argmin_fb<<<512, 256, 0, stream>>>(x, embed, out_q, out_idx, out_avg, out_commit);
    }
    finalize_kernel<<<1, 1024, 0, stream>>>(out_avg, out_commit, out_perp, out + 4260866);
}